// Round 12
// baseline (272.736 us; speedup 1.0000x reference)
//
#include <hip/hip_runtime.h>
#include <math.h>

typedef __attribute__((ext_vector_type(8))) short bf16x8;
typedef __attribute__((ext_vector_type(4))) float f32x4;

__device__ __forceinline__ unsigned short f2bf(float x) {
    unsigned int u = __float_as_uint(x);
    u += 0x7fff + ((u >> 16) & 1);           // RNE
    return (unsigned short)(u >> 16);
}
__device__ __forceinline__ float bf2f(unsigned short b) {
    return __uint_as_float(((unsigned int)b) << 16);
}
__device__ __forceinline__ unsigned int cvtpk(float a, float b) {
    unsigned int r;
    asm("v_cvt_pk_bf16_f32 %0, %1, %2" : "=v"(r) : "v"(a), "v"(b));
    return r;
}
__device__ __forceinline__ float fast_tanh(float x) {
    float e = __expf(2.0f * x);
    return 1.0f - 2.0f / (e + 1.0f);
}
__device__ __forceinline__ f32x4 mfma16(bf16x8 a, bf16x8 b, f32x4 c) {
    return __builtin_amdgcn_mfma_f32_16x16x32_bf16(a, b, c, 0, 0, 0);
}
union bfu { unsigned int w[4]; bf16x8 v; };
__device__ __forceinline__ bf16x8 cvt8(float4 u, float4 v) {
    bfu x;
    x.w[0] = cvtpk(u.x, u.y); x.w[1] = cvtpk(u.z, u.w);
    x.w[2] = cvtpk(v.x, v.y); x.w[3] = cvtpk(v.z, v.w);
    return x.v;
}
__device__ __forceinline__ void async16(void* lds, const void* g) {
    __builtin_amdgcn_global_load_lds(
        (const __attribute__((address_space(1))) unsigned int*)g,
        (__attribute__((address_space(3))) unsigned int*)lds, 16, 0, 0);
}

#define SBAR0 __builtin_amdgcn_sched_barrier(0)
#define BARX(vm) do { SBAR0; \
    asm volatile("s_waitcnt vmcnt(" #vm ") lgkmcnt(0)" ::: "memory"); \
    __builtin_amdgcn_s_barrier(); SBAR0; } while (0)

// ---------------------------------------------------------------------------
// Prep: weights -> frag-major bf16 (default k-map; unchanged from R11).
// ---------------------------------------------------------------------------
__global__ void prep_frag(const float* __restrict__ Wf, const float* __restrict__ W1,
                          const float* __restrict__ W2, const float* __restrict__ WL,
                          const float* __restrict__ WR,
                          unsigned short* __restrict__ WfF, unsigned short* __restrict__ W1F,
                          unsigned short* __restrict__ W2F, unsigned short* __restrict__ WLF,
                          unsigned short* __restrict__ WRF)
{
    int g = blockIdx.x * 256 + threadIdx.x;
    if (g >= 29696) return;
    int lane = g & 63, slot = g >> 6;
    int l15 = lane & 15, lkk = lane >> 4;

    unsigned short* dst;
    const float* W;
    int sl, NT, mode, Klim;
    if (slot < 16)       { dst = WfF; W = Wf; sl = slot;       NT = 8;  mode = 0; Klim = 39;  }
    else if (slot < 112) { dst = W1F; W = W1; sl = slot - 16;  NT = 8;  mode = 0; Klim = 384; }
    else if (slot < 144) { dst = W2F; W = W2; sl = slot - 112; NT = 8;  mode = 0; Klim = 128; }
    else if (slot < 304) { dst = WLF; W = WL; sl = slot - 144; NT = 16; mode = 1; Klim = 0;   }
    else                 { dst = WRF; W = WR; sl = slot - 304; NT = 16; mode = 1; Klim = 0;   }

    int ks = sl / NT;
    int n = (sl - ks * NT) * 16 + l15;
    int kb = ks * 32 + lkk * 8;
    unsigned short* o = dst + ((size_t)sl * 64 + lane) * 8;
    #pragma unroll
    for (int j = 0; j < 8; ++j) {
        int k = kb + j;
        float v;
        if (mode == 0) {
            v = (k < Klim) ? W[(size_t)k * 128 + n] : 0.0f;
        } else {
            if (k < 256)      v = W[(size_t)(39 + k) * 256 + n];
            else if (k < 295) v = W[(size_t)(k - 256) * 256 + n];
            else              v = 0.0f;
        }
        o[j] = f2bf(v);
    }
}

// ---------------------------------------------------------------------------
// Fused main: atom path now uses SWAPPED mfma operands (A=weights, B=data):
// lane's 4 acc regs = 4 consecutive CHANNELS of one atom -> vectorized 8B
// epilogue stores (16/wave vs 96 scalar). Tiles, swizzles, BARX rhythm and
// the gather path are byte-identical to R11.
// ---------------------------------------------------------------------------
__global__ __launch_bounds__(256, 4) void fused_main(
    const float* __restrict__ af, const float* __restrict__ am,
    const unsigned short* __restrict__ WfF, const float* __restrict__ bfe,
    const unsigned short* __restrict__ W1F, const float* __restrict__ b1,
    const unsigned short* __restrict__ W2F, const float* __restrict__ b2,
    const unsigned short* __restrict__ WLF, const float* __restrict__ bL,
    const unsigned short* __restrict__ WRF, const float* __restrict__ bR,
    const int* __restrict__ seg, const int* __restrict__ leaf_idx,
    const int* __restrict__ ring_idx, const int* __restrict__ rseg,
    float* __restrict__ out_mol, int* __restrict__ counts,
    float* __restrict__ out_leaf, float* __restrict__ out_ring,
    int N, int NL, int NRE, int nLeafBlocks, int NG, int T)
{
    __shared__ alignas(16) unsigned char LDSb[32768];
    __shared__ alignas(16) unsigned short Fb[2688];
    __shared__ int sseg[64];

    const int t = threadIdx.x, lane = t & 63, w = t >> 6;
    const int l15 = lane & 15, lk = lane >> 4;

    const unsigned long long bid = blockIdx.x;
    const int g_before = (int)(bid * (unsigned long long)NG / (unsigned long long)T);
    const int g_after  = (int)((bid + 1ull) * (unsigned long long)NG / (unsigned long long)T);
    const bool is_gather = (g_after > g_before);

    if (!is_gather) {
        // ================= ATOM PATH (swapped operands) =================
        const int ablk = (int)bid - g_before;
        const int r0 = ablk * 64;
        const int wr = w >> 1, wc = w & 1;
        unsigned char* Ebuf = LDSb;            // E tile, then H tile
        unsigned char* Mbuf = LDSb + 16384;    // 2x8KB chunks, then O
        unsigned char* M0 = Mbuf;
        unsigned char* M1 = Mbuf + 8192;

        auto stage8 = [&](unsigned char* buf, int cc) {
            #pragma unroll
            for (int p = 0; p < 2; ++p) {
                int i = t + p * 256;
                int r = i >> 3, sgl = i & 7;
                const float* src = am + ((size_t)min(r0 + r, N - 1) << 8)
                                      + cc * 32 + ((sgl ^ (r & 7)) << 2);
                async16(buf + (size_t)(p * 256 + w * 64) * 16, src);
            }
        };
        auto ldwb = [&](bf16x8* dst, const unsigned short* WB, int ks) {
            const bf16x8* Wp = (const bf16x8*)WB + ((size_t)ks * 8 + wc * 4) * 64 + lane;
            #pragma unroll
            for (int nt = 0; nt < 4; ++nt) dst[nt] = Wp[nt * 64];
        };
        // one K=32 step from a msg chunk (B = data, A = weights)
        auto cchunk = [&](const unsigned char* buf, const bf16x8* wbv, f32x4 (&acc)[2][4]) {
            #pragma unroll
            for (int tl = 0; tl < 2; ++tl) {
                int a = wr * 32 + tl * 16 + l15;
                int s0 = (lk * 2) ^ (a & 7), s1 = (lk * 2 + 1) ^ (a & 7);
                float4 x0 = *(const float4*)(buf + a * 128 + (s0 << 4));
                float4 x1 = *(const float4*)(buf + a * 128 + (s1 << 4));
                bf16x8 b = cvt8(x0, x1);
                #pragma unroll
                for (int nt = 0; nt < 4; ++nt) acc[tl][nt] = mfma16(wbv[nt], b, acc[tl][nt]);
            }
        };
        // one K=32 step from a bf16 swizzled tile (E or H)
        auto tstep = [&](const unsigned char* buf, int ks, const bf16x8* wbv, f32x4 (&acc)[2][4]) {
            #pragma unroll
            for (int tl = 0; tl < 2; ++tl) {
                int a = wr * 32 + tl * 16 + l15;
                int sg = (ks * 4 + lk) ^ (a & 15);
                bf16x8 b = *(const bf16x8*)(buf + a * 256 + (sg << 4));
                #pragma unroll
                for (int nt = 0; nt < 4; ++nt) acc[tl][nt] = mfma16(wbv[nt], b, acc[tl][nt]);
            }
        };
        // vectorized epilogue: 4 consecutive channels (one atom) per 8B store
        auto epi_store = [&](unsigned char* buf, int tl, int nt, float4 vv) {
            int a = wr * 32 + tl * 16 + l15;
            int g = wc * 8 + nt * 2 + (lk >> 1);
            uint2 o;
            o.x = cvtpk(vv.x, vv.y);
            o.y = cvtpk(vv.z, vv.w);
            *(uint2*)(buf + a * 256 + ((g ^ (a & 15)) << 4) + (lk & 1) * 8) = o;
        };

        // ---- prologue: contiguous af block load, weights, float4 biases ----
        float afv[10];
        #pragma unroll
        for (int p = 0; p < 10; ++p) {
            int i = t + p * 256;
            size_t gg = (size_t)r0 * 39 + i;
            afv[p] = (i < 2496 && gg < (size_t)N * 39) ? af[gg] : 0.f;
        }
        bf16x8 wf[2][4];
        ldwb(wf[0], WfF, 0);
        ldwb(wf[1], WfF, 1);
        float4 bfe4[4], b14[4], b24[4];
        #pragma unroll
        for (int nt = 0; nt < 4; ++nt) {
            int c0 = wc * 64 + nt * 16 + lk * 4;
            bfe4[nt] = *(const float4*)&bfe[c0];
            b14[nt]  = *(const float4*)&b1[c0];
            b24[nt]  = *(const float4*)&b2[c0];
        }
        if (t < 64) sseg[t] = (r0 + t < N) ? seg[r0 + t] : -1;
        bf16x8 wbA[4], wbB[4];
        ldwb(wbA, W1F, 0);
        SBAR0;
        stage8(M0, 0);
        stage8(M1, 1);
        SBAR0;
        #pragma unroll
        for (int p = 0; p < 10; ++p) {
            int i = t + p * 256;
            if (i < 2496) { int rf = i / 39, kf = i - rf * 39; Fb[rf * 40 + kf] = f2bf(afv[p]); }
        }
        if (t < 64) Fb[t * 40 + 39] = 0;
        if (t < 128) Fb[2560 + t] = 0;
        BARX(4);   // Fb visible; c0,c1 in flight

        // ---- phase 1: E = relu(af @ Wf + bf) -> Ebuf ----
        {
            f32x4 acc1[2][4] = {};
            #pragma unroll
            for (int ks = 0; ks < 2; ++ks) {
                #pragma unroll
                for (int tl = 0; tl < 2; ++tl) {
                    bf16x8 b = *(const bf16x8*)((const unsigned char*)Fb
                                  + (wr * 32 + tl * 16 + l15) * 80 + ks * 64 + lk * 16);
                    #pragma unroll
                    for (int nt = 0; nt < 4; ++nt)
                        acc1[tl][nt] = mfma16(wf[ks][nt], b, acc1[tl][nt]);
                }
            }
            #pragma unroll
            for (int nt = 0; nt < 4; ++nt)
                #pragma unroll
                for (int tl = 0; tl < 2; ++tl) {
                    float4 vv;
                    vv.x = fmaxf(acc1[tl][nt][0] + bfe4[nt].x, 0.f);
                    vv.y = fmaxf(acc1[tl][nt][1] + bfe4[nt].y, 0.f);
                    vv.z = fmaxf(acc1[tl][nt][2] + bfe4[nt].z, 0.f);
                    vv.w = fmaxf(acc1[tl][nt][3] + bfe4[nt].w, 0.f);
                    epi_store(Ebuf, tl, nt, vv);
                }
        }
        BARX(4);   // E visible; c0,c1 still in flight

        // ---- phase 2: H = relu([E | msg] @ W1 + b1) ----
        f32x4 acc2[2][4] = {};
        ldwb(wbB, W1F, 1); SBAR0; tstep(Ebuf, 0, wbA, acc2);
        ldwb(wbA, W1F, 2); SBAR0; tstep(Ebuf, 1, wbB, acc2);
        ldwb(wbB, W1F, 3); SBAR0; tstep(Ebuf, 2, wbA, acc2);
        ldwb(wbA, W1F, 4); SBAR0; tstep(Ebuf, 3, wbB, acc2);
        BARX(4);

        ldwb(wbB, W1F, 5);  SBAR0; cchunk(M0, wbA, acc2);
        BARX(4); stage8(M0, 2); SBAR0;
        ldwb(wbA, W1F, 6);  SBAR0; cchunk(M1, wbB, acc2);
        BARX(4); stage8(M1, 3); SBAR0;
        ldwb(wbB, W1F, 7);  SBAR0; cchunk(M0, wbA, acc2);
        BARX(4); stage8(M0, 4); SBAR0;
        ldwb(wbA, W1F, 8);  SBAR0; cchunk(M1, wbB, acc2);
        BARX(4); stage8(M1, 5); SBAR0;
        ldwb(wbB, W1F, 9);  SBAR0; cchunk(M0, wbA, acc2);
        BARX(4); stage8(M0, 6); SBAR0;
        ldwb(wbA, W1F, 10); SBAR0; cchunk(M1, wbB, acc2);
        BARX(4); stage8(M1, 7); SBAR0;
        ldwb(wbB, W1F, 11); SBAR0; cchunk(M0, wbA, acc2);
        BARX(4);
        ldwb(wbA, W2F, 0);  SBAR0; cchunk(M1, wbB, acc2);

        // ---- H epilogue -> Ebuf (E dead) ----
        #pragma unroll
        for (int nt = 0; nt < 4; ++nt)
            #pragma unroll
            for (int tl = 0; tl < 2; ++tl) {
                float4 vv;
                vv.x = fmaxf(acc2[tl][nt][0] + b14[nt].x, 0.f);
                vv.y = fmaxf(acc2[tl][nt][1] + b14[nt].y, 0.f);
                vv.z = fmaxf(acc2[tl][nt][2] + b14[nt].z, 0.f);
                vv.w = fmaxf(acc2[tl][nt][3] + b14[nt].w, 0.f);
                epi_store(Ebuf, tl, nt, vv);
            }
        BARX(4);   // H visible; W2F ks0 frags in flight

        // ---- phase 3: O = tanh(H @ W2 + b2) -> Mbuf overlay ----
        {
            f32x4 acc3[2][4] = {};
            ldwb(wbB, W2F, 1); SBAR0; tstep(Ebuf, 0, wbA, acc3);
            ldwb(wbA, W2F, 2); SBAR0; tstep(Ebuf, 1, wbB, acc3);
            ldwb(wbB, W2F, 3); SBAR0; tstep(Ebuf, 2, wbA, acc3);
            tstep(Ebuf, 3, wbB, acc3);
            #pragma unroll
            for (int nt = 0; nt < 4; ++nt)
                #pragma unroll
                for (int tl = 0; tl < 2; ++tl) {
                    float4 vv;
                    vv.x = fast_tanh(acc3[tl][nt][0] + b24[nt].x);
                    vv.y = fast_tanh(acc3[tl][nt][1] + b24[nt].y);
                    vv.z = fast_tanh(acc3[tl][nt][2] + b24[nt].z);
                    vv.w = fast_tanh(acc3[tl][nt][3] + b24[nt].w);
                    epi_store(Mbuf, tl, nt, vv);
                }
        }
        asm volatile("s_waitcnt lgkmcnt(0)" ::: "memory");
        SBAR0;

        // ---- pooling: wave pools its 32-row x 64-col quadrant of O ----
        {
            const int c = wc * 64 + lane;
            int cur = -1, runlen = 0;
            float s = 0.f, m = 0.f;
            #pragma unroll 1
            for (int a2 = 0; a2 < 32; ++a2) {
                int arow = wr * 32 + a2;
                int sg = sseg[arow];
                if (sg < 0) break;
                int byte = arow * 256 + ((((c >> 3) ^ (arow & 15))) << 4) + (c & 7) * 2;
                float v = bf2f(*(const unsigned short*)(Mbuf + byte));
                if (sg != cur) {
                    if (cur >= 0) {
                        atomicAdd(&out_mol[(size_t)cur * 256 + c], s);
                        atomicMax((unsigned int*)&out_mol[(size_t)cur * 256 + 128 + c],
                                  __float_as_uint(m + 2.0f));
                        if (wc == 0 && lane == 0) atomicAdd(&counts[cur], runlen);
                    }
                    cur = sg; s = v; m = v; runlen = 1;
                } else {
                    s += v; m = fmaxf(m, v); ++runlen;
                }
            }
            if (cur >= 0) {
                atomicAdd(&out_mol[(size_t)cur * 256 + c], s);
                atomicMax((unsigned int*)&out_mol[(size_t)cur * 256 + 128 + c],
                          __float_as_uint(m + 2.0f));
                if (wc == 0 && lane == 0) atomicAdd(&counts[cur], runlen);
            }
        }
        return;
    }

    // ================= GATHER PATH (leaf / ring) — unchanged from R11 =======
    {
        const int gblk = g_before;
        const bool ring = gblk >= nLeafBlocks;
        const unsigned short* WF = ring ? WRF : WLF;
        const float* bv = ring ? bR : bL;
        const int* idx = ring ? ring_idx : leaf_idx;
        const int NROWS = ring ? NRE : NL;
        const int blk = ring ? gblk - nLeafBlocks : gblk;
        const int r0 = blk * 64;
        const int wrg = w & 1, wcg = w >> 1;
        const int lrow = l15;

        if (t < 64) sseg[t] = idx[min(r0 + t, NROWS - 1)];
        __syncthreads();

        unsigned char* Xb = LDSb;
        #pragma unroll
        for (int p = 0; p < 16; ++p) {
            int i = t + p * 256;
            int r = i >> 6, kq = i & 63;
            float4 v = *(const float4*)(am + ((size_t)sseg[r] << 8) + kq * 4);
            uint2 u;
            u.x = cvtpk(v.x, v.y); u.y = cvtpk(v.z, v.w);
            *(uint2*)(Xb + r * 512 + (((kq >> 1) ^ (r & 15)) << 4) + (kq & 1) * 8) = u;
        }
        #pragma unroll
        for (int p = 0; p < 10; ++p) {
            int i = t + p * 256;
            if (i < 2496) {
                int rf = i / 39, kf = i - rf * 39;
                Fb[rf * 40 + kf] = f2bf(af[(size_t)sseg[rf] * 39 + kf]);
            }
        }
        if (t < 64) Fb[t * 40 + 39] = 0;
        if (t < 128) Fb[2560 + t] = 0;
        __syncthreads();

        f32x4 acc[2][8] = {};
        #pragma unroll
        for (int ks = 0; ks < 8; ++ks) {
            bf16x8 wb[8];
            const bf16x8* B = (const bf16x8*)WF + (ks * 16 + wcg * 8) * 64 + lane;
            #pragma unroll
            for (int nt = 0; nt < 8; ++nt) wb[nt] = B[nt * 64];
            #pragma unroll
            for (int mt = 0; mt < 2; ++mt) {
                int row = wrg * 32 + mt * 16 + lrow;
                bf16x8 a = *(const bf16x8*)(Xb + row * 512 + ((((ks * 4 + lk) ^ (row & 15))) << 4));
                #pragma unroll
                for (int nt = 0; nt < 8; ++nt) acc[mt][nt] = mfma16(a, wb[nt], acc[mt][nt]);
            }
        }
        #pragma unroll
        for (int ks = 8; ks < 10; ++ks) {
            bf16x8 wb[8];
            const bf16x8* B = (const bf16x8*)WF + (ks * 16 + wcg * 8) * 64 + lane;
            #pragma unroll
            for (int nt = 0; nt < 8; ++nt) wb[nt] = B[nt * 64];
            #pragma unroll
            for (int mt = 0; mt < 2; ++mt) {
                int row = wrg * 32 + mt * 16 + lrow;
                bf16x8 a = *(const bf16x8*)((const unsigned char*)Fb
                              + row * 80 + (ks - 8) * 64 + lk * 16);
                #pragma unroll
                for (int nt = 0; nt < 8; ++nt) acc[mt][nt] = mfma16(a, wb[nt], acc[mt][nt]);
            }
        }

        if (!ring) {
            #pragma unroll
            for (int nt = 0; nt < 8; ++nt) {
                int c = wcg * 128 + nt * 16 + lrow;
                float bias = bv[c];
                #pragma unroll
                for (int mt = 0; mt < 2; ++mt) {
                    #pragma unroll
                    for (int r = 0; r < 4; ++r) {
                        int row = r0 + wrg * 32 + mt * 16 + lk * 4 + r;
                        if (row < NROWS)
                            out_leaf[(size_t)row * 256 + c] = fast_tanh(acc[mt][nt][r] + bias);
                    }
                }
            }
        } else {
            int sg[2][4];
            #pragma unroll
            for (int mt = 0; mt < 2; ++mt)
                #pragma unroll
                for (int r = 0; r < 4; ++r) {
                    int rr = r0 + wrg * 32 + mt * 16 + lk * 4 + r;
                    sg[mt][r] = (rr < NROWS) ? rseg[rr] : -1;
                }
            #pragma unroll
            for (int nt = 0; nt < 8; ++nt) {
                int c = wcg * 128 + nt * 16 + lrow;
                float bias = bv[c];
                #pragma unroll
                for (int mt = 0; mt < 2; ++mt) {
                    int cur = -1; float accv = 0.0f;
                    #pragma unroll
                    for (int r = 0; r < 4; ++r) {
                        float v = fast_tanh(acc[mt][nt][r] + bias);
                        int s = sg[mt][r];
                        if (s != cur) {
                            if (cur >= 0) atomicAdd(&out_ring[(size_t)cur * 256 + c], accv);
                            cur = s; accv = v;
                        } else accv += v;
                    }
                    if (cur >= 0) atomicAdd(&out_ring[(size_t)cur * 256 + c], accv);
                }
            }
        }
    }
}

// ---------------------------------------------------------------------------
// Finalize molecule embedding in-place: avg = sum/count, max decode
// ---------------------------------------------------------------------------
__global__ void finalize_kernel(float* __restrict__ out, const int* __restrict__ counts, int M)
{
    int tid = blockIdx.x * blockDim.x + threadIdx.x;
    if (tid >= M * 128) return;
    int m = tid >> 7, c = tid & 127;
    int cnt = counts[m];
    float denom = (cnt > 0) ? (float)cnt : 1.0f;
    float s  = out[(size_t)m * 256 + c];
    float mr = out[(size_t)m * 256 + 128 + c];
    out[(size_t)m * 256 + c] = s / denom;
    out[(size_t)m * 256 + 128 + c] = (cnt > 0) ? (mr - 2.0f) : 0.0f;
}

extern "C" void kernel_launch(void* const* d_in, const int* in_sizes, int n_in,
                              void* d_out, int out_size, void* d_ws, size_t ws_size,
                              hipStream_t stream) {
    const float* af = (const float*)d_in[0];
    const float* am = (const float*)d_in[1];
    const float* Wf = (const float*)d_in[2];
    const float* bfe = (const float*)d_in[3];
    const float* W1 = (const float*)d_in[4];
    const float* b1 = (const float*)d_in[5];
    const float* W2 = (const float*)d_in[6];
    const float* b2 = (const float*)d_in[7];
    const float* WL = (const float*)d_in[8];
    const float* bL = (const float*)d_in[9];
    const float* WR = (const float*)d_in[10];
    const float* bR = (const float*)d_in[11];
    const int* seg      = (const int*)d_in[12];
    const int* leaf_idx = (const int*)d_in[13];
    const int* ring_idx = (const int*)d_in[14];
    const int* ring_seg = (const int*)d_in[15];

    const int N   = in_sizes[0] / 39;   // 300000
    const int NL  = in_sizes[13];       // 50000
    const int NRE = in_sizes[14];       // 120000
    const int M   = 10000;
    const int NR  = 20000;

    float* out = (float*)d_out;
    float* out_mol  = out;
    float* out_leaf = out + (size_t)M * 256;
    float* out_ring = out + (size_t)M * 256 + (size_t)NL * 256;

    // ws layout (16B-aligned offsets)
    int* counts = (int*)d_ws;                                       // 40 KB
    unsigned short* WfF = (unsigned short*)((char*)d_ws + 40960);   // 16 KB
    unsigned short* W1F = (unsigned short*)((char*)d_ws + 57344);   // 96 KB
    unsigned short* W2F = (unsigned short*)((char*)d_ws + 155648);  // 32 KB
    unsigned short* WLF = (unsigned short*)((char*)d_ws + 188416);  // 160 KB
    unsigned short* WRF = (unsigned short*)((char*)d_ws + 352256);  // 160 KB

    hipMemsetAsync(out_mol, 0, (size_t)M * 256 * sizeof(float), stream);
    hipMemsetAsync(out_ring, 0, (size_t)NR * 256 * sizeof(float), stream);
    hipMemsetAsync(counts, 0, (size_t)M * sizeof(int), stream);

    prep_frag<<<(29696 + 255) / 256, 256, 0, stream>>>(
        Wf, W1, W2, WL, WR, WfF, W1F, W2F, WLF, WRF);

    const int NA = (N + 63) / 64;
    const int nLeafBlocks = (NL + 63) / 64;
    const int nRingBlocks = (NRE + 63) / 64;
    const int NG = nLeafBlocks + nRingBlocks;
    const int T  = NA + NG;

    fused_main<<<T, 256, 0, stream>>>(
        af, am, WfF, bfe, W1F, b1, W2F, b2, WLF, bL, WRF, bR,
        seg, leaf_idx, ring_idx, ring_seg,
        out_mol, counts, out_leaf, out_ring,
        N, NL, NRE, nLeafBlocks, NG, T);

    finalize_kernel<<<(M * 128 + 255) / 256, 256, 0, stream>>>(out_mol, counts, M);
}

// Round 13
// 242.082 us; speedup vs baseline: 1.1266x; 1.1266x over previous
//
#include <hip/hip_runtime.h>
#include <math.h>

typedef __attribute__((ext_vector_type(8))) short bf16x8;
typedef __attribute__((ext_vector_type(4))) float f32x4;

__device__ __forceinline__ unsigned short f2bf(float x) {
    unsigned int u = __float_as_uint(x);
    u += 0x7fff + ((u >> 16) & 1);           // RNE
    return (unsigned short)(u >> 16);
}
__device__ __forceinline__ float bf2f(unsigned short b) {
    return __uint_as_float(((unsigned int)b) << 16);
}
__device__ __forceinline__ unsigned int cvtpk(float a, float b) {
    unsigned int r;
    asm("v_cvt_pk_bf16_f32 %0, %1, %2" : "=v"(r) : "v"(a), "v"(b));
    return r;
}
__device__ __forceinline__ float fast_tanh(float x) {
    float e = __expf(2.0f * x);
    return 1.0f - 2.0f / (e + 1.0f);
}
__device__ __forceinline__ f32x4 mfma16(bf16x8 a, bf16x8 b, f32x4 c) {
    return __builtin_amdgcn_mfma_f32_16x16x32_bf16(a, b, c, 0, 0, 0);
}
union bfu { unsigned int w[4]; bf16x8 v; };
__device__ __forceinline__ bf16x8 cvt8(float4 u, float4 v) {
    bfu x;
    x.w[0] = cvtpk(u.x, u.y); x.w[1] = cvtpk(u.z, u.w);
    x.w[2] = cvtpk(v.x, v.y); x.w[3] = cvtpk(v.z, v.w);
    return x.v;
}
__device__ __forceinline__ void async16(void* lds, const void* g) {
    __builtin_amdgcn_global_load_lds(
        (const __attribute__((address_space(1))) unsigned int*)g,
        (__attribute__((address_space(3))) unsigned int*)lds, 16, 0, 0);
}

#define SBAR0 __builtin_amdgcn_sched_barrier(0)
#define BARX(vm) do { SBAR0; \
    asm volatile("s_waitcnt vmcnt(" #vm ") lgkmcnt(0)" ::: "memory"); \
    __builtin_amdgcn_s_barrier(); SBAR0; } while (0)

// ---------------------------------------------------------------------------
// Prep: weights -> frag-major bf16 (default k-map; R4/R11 layout).
// ---------------------------------------------------------------------------
__global__ void prep_frag(const float* __restrict__ Wf, const float* __restrict__ W1,
                          const float* __restrict__ W2, const float* __restrict__ WL,
                          const float* __restrict__ WR,
                          unsigned short* __restrict__ WfF, unsigned short* __restrict__ W1F,
                          unsigned short* __restrict__ W2F, unsigned short* __restrict__ WLF,
                          unsigned short* __restrict__ WRF)
{
    int g = blockIdx.x * 256 + threadIdx.x;
    if (g >= 29696) return;
    int lane = g & 63, slot = g >> 6;
    int l15 = lane & 15, lkk = lane >> 4;

    unsigned short* dst;
    const float* W;
    int sl, NT, mode, Klim;
    if (slot < 16)       { dst = WfF; W = Wf; sl = slot;       NT = 8;  mode = 0; Klim = 39;  }
    else if (slot < 112) { dst = W1F; W = W1; sl = slot - 16;  NT = 8;  mode = 0; Klim = 384; }
    else if (slot < 144) { dst = W2F; W = W2; sl = slot - 112; NT = 8;  mode = 0; Klim = 128; }
    else if (slot < 304) { dst = WLF; W = WL; sl = slot - 144; NT = 16; mode = 1; Klim = 0;   }
    else                 { dst = WRF; W = WR; sl = slot - 304; NT = 16; mode = 1; Klim = 0;   }

    int ks = sl / NT;
    int n = (sl - ks * NT) * 16 + l15;
    int kb = ks * 32 + lkk * 8;
    unsigned short* o = dst + ((size_t)sl * 64 + lane) * 8;
    #pragma unroll
    for (int j = 0; j < 8; ++j) {
        int k = kb + j;
        float v;
        if (mode == 0) {
            v = (k < Klim) ? W[(size_t)k * 128 + n] : 0.0f;
        } else {
            if (k < 256)      v = W[(size_t)(39 + k) * 256 + n];
            else if (k < 295) v = W[(size_t)(k - 256) * 256 + n];
            else              v = 0.0f;
        }
        o[j] = f2bf(v);
    }
}

// ---------------------------------------------------------------------------
// Fused main: Bresenham-interleaved atom / gather blocks, 4 blocks/CU.
// ALL A-operand global reads are row-contiguous (no 16-scattered-line instrs):
//   atom: af staged as one contiguous block; msg via global_load_lds.
//   gather: msg+af rows staged to LDS with per-row coalesced loads.
// (Exact R11 configuration — best measured: fused ~260 us, total ~242 us.)
// ---------------------------------------------------------------------------
__global__ __launch_bounds__(256, 4) void fused_main(
    const float* __restrict__ af, const float* __restrict__ am,
    const unsigned short* __restrict__ WfF, const float* __restrict__ bfe,
    const unsigned short* __restrict__ W1F, const float* __restrict__ b1,
    const unsigned short* __restrict__ W2F, const float* __restrict__ b2,
    const unsigned short* __restrict__ WLF, const float* __restrict__ bL,
    const unsigned short* __restrict__ WRF, const float* __restrict__ bR,
    const int* __restrict__ seg, const int* __restrict__ leaf_idx,
    const int* __restrict__ ring_idx, const int* __restrict__ rseg,
    float* __restrict__ out_mol, int* __restrict__ counts,
    float* __restrict__ out_leaf, float* __restrict__ out_ring,
    int N, int NL, int NRE, int nLeafBlocks, int NG, int T)
{
    __shared__ alignas(16) unsigned char LDSb[32768];   // atom: Ebuf|Mbuf; gather: X tile
    __shared__ alignas(16) unsigned short Fb[2688];     // af tile [64][40] + pads
    __shared__ int sseg[64];

    const int t = threadIdx.x, lane = t & 63, w = t >> 6;
    const int lrow = lane & 15, lk = lane >> 4;

    const unsigned long long bid = blockIdx.x;
    const int g_before = (int)(bid * (unsigned long long)NG / (unsigned long long)T);
    const int g_after  = (int)((bid + 1ull) * (unsigned long long)NG / (unsigned long long)T);
    const bool is_gather = (g_after > g_before);

    if (!is_gather) {
        // ================= ATOM PATH =================
        const int ablk = (int)bid - g_before;
        const int r0 = ablk * 64;
        const int wr = w >> 1, wc = w & 1;
        unsigned char* Ebuf = LDSb;            // E tile, then H tile
        unsigned char* Mbuf = LDSb + 16384;    // 2x8KB chunks, then O
        unsigned char* M0 = Mbuf;
        unsigned char* M1 = Mbuf + 8192;

        auto stage8 = [&](unsigned char* buf, int cc) {
            #pragma unroll
            for (int p = 0; p < 2; ++p) {
                int i = t + p * 256;
                int r = i >> 3, sgl = i & 7;
                const float* src = am + ((size_t)min(r0 + r, N - 1) << 8)
                                      + cc * 32 + ((sgl ^ (r & 7)) << 2);
                async16(buf + (size_t)(p * 256 + w * 64) * 16, src);
            }
        };
        auto ldwb = [&](bf16x8* dst, const unsigned short* WB, int ks) {
            const bf16x8* Wp = (const bf16x8*)WB + ((size_t)ks * 8 + wc * 4) * 64 + lane;
            #pragma unroll
            for (int nt = 0; nt < 4; ++nt) dst[nt] = Wp[nt * 64];
        };
        auto cchunk = [&](const unsigned char* buf, const bf16x8* wbv, f32x4 (&acc)[2][4]) {
            #pragma unroll
            for (int mt = 0; mt < 2; ++mt) {
                int row = wr * 32 + mt * 16 + lrow;
                int s0 = (lk * 2) ^ (row & 7), s1 = (lk * 2 + 1) ^ (row & 7);
                float4 x0 = *(const float4*)(buf + row * 128 + (s0 << 4));
                float4 x1 = *(const float4*)(buf + row * 128 + (s1 << 4));
                bf16x8 a = cvt8(x0, x1);
                #pragma unroll
                for (int nt = 0; nt < 4; ++nt) acc[mt][nt] = mfma16(a, wbv[nt], acc[mt][nt]);
            }
        };
        auto tstep = [&](const unsigned char* buf, int ks, const bf16x8* wbv, f32x4 (&acc)[2][4]) {
            #pragma unroll
            for (int mt = 0; mt < 2; ++mt) {
                int row = wr * 32 + mt * 16 + lrow;
                int sg = (ks * 4 + lk) ^ (row & 15);
                bf16x8 a = *(const bf16x8*)(buf + row * 256 + (sg << 4));
                #pragma unroll
                for (int nt = 0; nt < 4; ++nt) acc[mt][nt] = mfma16(a, wbv[nt], acc[mt][nt]);
            }
        };
        auto tile_write = [&](unsigned char* buf, int row, int c, float v) {
            int byte = row * 256 + ((((c >> 3) ^ (row & 15))) << 4) + (c & 7) * 2;
            *(unsigned short*)(buf + byte) = f2bf(v);
        };

        // ---- prologue: contiguous af block load (oldest VMEM), weights, seg ----
        float afv[10];
        #pragma unroll
        for (int p = 0; p < 10; ++p) {
            int i = t + p * 256;
            size_t g = (size_t)r0 * 39 + i;
            afv[p] = (i < 2496 && g < (size_t)N * 39) ? af[g] : 0.f;
        }
        bf16x8 wf[2][4];
        ldwb(wf[0], WfF, 0);
        ldwb(wf[1], WfF, 1);
        float bfe_r[4], b1_r[4], b2_r[4];
        #pragma unroll
        for (int nt = 0; nt < 4; ++nt) {
            int c = wc * 64 + nt * 16 + lrow;
            bfe_r[nt] = bfe[c]; b1_r[nt] = b1[c]; b2_r[nt] = b2[c];
        }
        if (t < 64) sseg[t] = (r0 + t < N) ? seg[r0 + t] : -1;
        bf16x8 wbA[4], wbB[4];
        ldwb(wbA, W1F, 0);
        SBAR0;
        stage8(M0, 0);                 // newest VMEM: 4 asyncs stay in flight
        stage8(M1, 1);
        SBAR0;
        // write af tile (forces af retirements; asyncs are newer -> unaffected)
        #pragma unroll
        for (int p = 0; p < 10; ++p) {
            int i = t + p * 256;
            if (i < 2496) { int rf = i / 39, kf = i - rf * 39; Fb[rf * 40 + kf] = f2bf(afv[p]); }
        }
        if (t < 64) Fb[t * 40 + 39] = 0;
        if (t < 128) Fb[2560 + t] = 0;
        BARX(4);   // Fb visible; c0,c1 in flight

        // ---- phase 1: E = relu(af @ Wf + bf) -> Ebuf (A-frags from Fb) ----
        {
            f32x4 acc1[2][4] = {};
            #pragma unroll
            for (int ks = 0; ks < 2; ++ks) {
                bf16x8 a0 = *(const bf16x8*)((const unsigned char*)Fb
                              + (wr * 32 + lrow) * 80 + ks * 64 + lk * 16);
                bf16x8 a1 = *(const bf16x8*)((const unsigned char*)Fb
                              + (wr * 32 + 16 + lrow) * 80 + ks * 64 + lk * 16);
                #pragma unroll
                for (int nt = 0; nt < 4; ++nt) {
                    acc1[0][nt] = mfma16(a0, wf[ks][nt], acc1[0][nt]);
                    acc1[1][nt] = mfma16(a1, wf[ks][nt], acc1[1][nt]);
                }
            }
            #pragma unroll
            for (int nt = 0; nt < 4; ++nt) {
                int c = wc * 64 + nt * 16 + lrow;
                #pragma unroll
                for (int mt = 0; mt < 2; ++mt)
                    #pragma unroll
                    for (int rr = 0; rr < 4; ++rr) {
                        int row = wr * 32 + mt * 16 + lk * 4 + rr;
                        tile_write(Ebuf, row, c, fmaxf(acc1[mt][nt][rr] + bfe_r[nt], 0.f));
                    }
            }
        }
        BARX(4);   // E visible; c0,c1 still in flight

        // ---- phase 2: H = relu([E | msg] @ W1 + b1) ----
        f32x4 acc2[2][4] = {};
        ldwb(wbB, W1F, 1); SBAR0; tstep(Ebuf, 0, wbA, acc2);
        ldwb(wbA, W1F, 2); SBAR0; tstep(Ebuf, 1, wbB, acc2);
        ldwb(wbB, W1F, 3); SBAR0; tstep(Ebuf, 2, wbA, acc2);
        ldwb(wbA, W1F, 4); SBAR0; tstep(Ebuf, 3, wbB, acc2);
        BARX(4);

        ldwb(wbB, W1F, 5);  SBAR0; cchunk(M0, wbA, acc2);
        BARX(4); stage8(M0, 2); SBAR0;
        ldwb(wbA, W1F, 6);  SBAR0; cchunk(M1, wbB, acc2);
        BARX(4); stage8(M1, 3); SBAR0;
        ldwb(wbB, W1F, 7);  SBAR0; cchunk(M0, wbA, acc2);
        BARX(4); stage8(M0, 4); SBAR0;
        ldwb(wbA, W1F, 8);  SBAR0; cchunk(M1, wbB, acc2);
        BARX(4); stage8(M1, 5); SBAR0;
        ldwb(wbB, W1F, 9);  SBAR0; cchunk(M0, wbA, acc2);
        BARX(4); stage8(M0, 6); SBAR0;
        ldwb(wbA, W1F, 10); SBAR0; cchunk(M1, wbB, acc2);
        BARX(4); stage8(M1, 7); SBAR0;
        ldwb(wbB, W1F, 11); SBAR0; cchunk(M0, wbA, acc2);
        BARX(4);
        ldwb(wbA, W2F, 0);  SBAR0; cchunk(M1, wbB, acc2);

        // ---- H epilogue -> Ebuf (E dead) ----
        #pragma unroll
        for (int nt = 0; nt < 4; ++nt) {
            int c = wc * 64 + nt * 16 + lrow;
            #pragma unroll
            for (int mt = 0; mt < 2; ++mt)
                #pragma unroll
                for (int rr = 0; rr < 4; ++rr) {
                    int row = wr * 32 + mt * 16 + lk * 4 + rr;
                    tile_write(Ebuf, row, c, fmaxf(acc2[mt][nt][rr] + b1_r[nt], 0.f));
                }
        }
        BARX(4);   // H visible; W2F ks0 frags in flight

        // ---- phase 3: O = tanh(H @ W2 + b2) -> Mbuf overlay ----
        {
            f32x4 acc3[2][4] = {};
            ldwb(wbB, W2F, 1); SBAR0; tstep(Ebuf, 0, wbA, acc3);
            ldwb(wbA, W2F, 2); SBAR0; tstep(Ebuf, 1, wbB, acc3);
            ldwb(wbB, W2F, 3); SBAR0; tstep(Ebuf, 2, wbA, acc3);
            tstep(Ebuf, 3, wbB, acc3);
            #pragma unroll
            for (int nt = 0; nt < 4; ++nt) {
                int c = wc * 64 + nt * 16 + lrow;
                #pragma unroll
                for (int mt = 0; mt < 2; ++mt)
                    #pragma unroll
                    for (int rr = 0; rr < 4; ++rr) {
                        int row = wr * 32 + mt * 16 + lk * 4 + rr;
                        tile_write(Mbuf, row, c, fast_tanh(acc3[mt][nt][rr] + b2_r[nt]));
                    }
            }
        }
        asm volatile("s_waitcnt lgkmcnt(0)" ::: "memory");
        SBAR0;

        // ---- pooling ----
        {
            const int c = wc * 64 + lane;
            int cur = -1, runlen = 0;
            float s = 0.f, m = 0.f;
            #pragma unroll 1
            for (int a2 = 0; a2 < 32; ++a2) {
                int arow = wr * 32 + a2;
                int sg = sseg[arow];
                if (sg < 0) break;
                int byte = arow * 256 + ((((c >> 3) ^ (arow & 15))) << 4) + (c & 7) * 2;
                float v = bf2f(*(const unsigned short*)(Mbuf + byte));
                if (sg != cur) {
                    if (cur >= 0) {
                        atomicAdd(&out_mol[(size_t)cur * 256 + c], s);
                        atomicMax((unsigned int*)&out_mol[(size_t)cur * 256 + 128 + c],
                                  __float_as_uint(m + 2.0f));
                        if (wc == 0 && lane == 0) atomicAdd(&counts[cur], runlen);
                    }
                    cur = sg; s = v; m = v; runlen = 1;
                } else {
                    s += v; m = fmaxf(m, v); ++runlen;
                }
            }
            if (cur >= 0) {
                atomicAdd(&out_mol[(size_t)cur * 256 + c], s);
                atomicMax((unsigned int*)&out_mol[(size_t)cur * 256 + 128 + c],
                          __float_as_uint(m + 2.0f));
                if (wc == 0 && lane == 0) atomicAdd(&counts[cur], runlen);
            }
        }
        return;
    }

    // ================= GATHER PATH (leaf / ring) =================
    {
        const int gblk = g_before;
        const bool ring = gblk >= nLeafBlocks;
        const unsigned short* WF = ring ? WRF : WLF;
        const float* bv = ring ? bR : bL;
        const int* idx = ring ? ring_idx : leaf_idx;
        const int NROWS = ring ? NRE : NL;
        const int blk = ring ? gblk - nLeafBlocks : gblk;
        const int r0 = blk * 64;
        const int wrg = w & 1, wcg = w >> 1;      // rows wrg*32, cols wcg*128

        if (t < 64) sseg[t] = idx[min(r0 + t, NROWS - 1)];
        __syncthreads();

        // ---- stage msg rows -> swizzled bf16 X tile (row-contiguous loads) ----
        unsigned char* Xb = LDSb;
        #pragma unroll
        for (int p = 0; p < 16; ++p) {
            int i = t + p * 256;
            int r = i >> 6, kq = i & 63;
            float4 v = *(const float4*)(am + ((size_t)sseg[r] << 8) + kq * 4);
            uint2 u;
            u.x = cvtpk(v.x, v.y); u.y = cvtpk(v.z, v.w);
            *(uint2*)(Xb + r * 512 + (((kq >> 1) ^ (r & 15)) << 4) + (kq & 1) * 8) = u;
        }
        // ---- stage af rows -> Fb tile ----
        #pragma unroll
        for (int p = 0; p < 10; ++p) {
            int i = t + p * 256;
            if (i < 2496) {
                int rf = i / 39, kf = i - rf * 39;
                Fb[rf * 40 + kf] = f2bf(af[(size_t)sseg[rf] * 39 + kf]);
            }
        }
        if (t < 64) Fb[t * 40 + 39] = 0;
        if (t < 128) Fb[2560 + t] = 0;
        __syncthreads();

        f32x4 acc[2][8] = {};
        #pragma unroll
        for (int ks = 0; ks < 8; ++ks) {          // msg K-part from LDS
            bf16x8 wb[8];
            const bf16x8* B = (const bf16x8*)WF + (ks * 16 + wcg * 8) * 64 + lane;
            #pragma unroll
            for (int nt = 0; nt < 8; ++nt) wb[nt] = B[nt * 64];
            #pragma unroll
            for (int mt = 0; mt < 2; ++mt) {
                int row = wrg * 32 + mt * 16 + lrow;
                bf16x8 a = *(const bf16x8*)(Xb + row * 512 + ((((ks * 4 + lk) ^ (row & 15))) << 4));
                #pragma unroll
                for (int nt = 0; nt < 8; ++nt) acc[mt][nt] = mfma16(a, wb[nt], acc[mt][nt]);
            }
        }
        #pragma unroll
        for (int ks = 8; ks < 10; ++ks) {         // af K-part from Fb
            bf16x8 wb[8];
            const bf16x8* B = (const bf16x8*)WF + (ks * 16 + wcg * 8) * 64 + lane;
            #pragma unroll
            for (int nt = 0; nt < 8; ++nt) wb[nt] = B[nt * 64];
            #pragma unroll
            for (int mt = 0; mt < 2; ++mt) {
                int row = wrg * 32 + mt * 16 + lrow;
                bf16x8 a = *(const bf16x8*)((const unsigned char*)Fb
                              + row * 80 + (ks - 8) * 64 + lk * 16);
                #pragma unroll
                for (int nt = 0; nt < 8; ++nt) acc[mt][nt] = mfma16(a, wb[nt], acc[mt][nt]);
            }
        }

        if (!ring) {
            #pragma unroll
            for (int nt = 0; nt < 8; ++nt) {
                int c = wcg * 128 + nt * 16 + lrow;
                float bias = bv[c];
                #pragma unroll
                for (int mt = 0; mt < 2; ++mt) {
                    #pragma unroll
                    for (int r = 0; r < 4; ++r) {
                        int row = r0 + wrg * 32 + mt * 16 + lk * 4 + r;
                        if (row < NROWS)
                            out_leaf[(size_t)row * 256 + c] = fast_tanh(acc[mt][nt][r] + bias);
                    }
                }
            }
        } else {
            int sg[2][4];
            #pragma unroll
            for (int mt = 0; mt < 2; ++mt)
                #pragma unroll
                for (int r = 0; r < 4; ++r) {
                    int rr = r0 + wrg * 32 + mt * 16 + lk * 4 + r;
                    sg[mt][r] = (rr < NROWS) ? rseg[rr] : -1;
                }
            #pragma unroll
            for (int nt = 0; nt < 8; ++nt) {
                int c = wcg * 128 + nt * 16 + lrow;
                float bias = bv[c];
                #pragma unroll
                for (int mt = 0; mt < 2; ++mt) {
                    int cur = -1; float accv = 0.0f;
                    #pragma unroll
                    for (int r = 0; r < 4; ++r) {
                        float v = fast_tanh(acc[mt][nt][r] + bias);
                        int s = sg[mt][r];
                        if (s != cur) {
                            if (cur >= 0) atomicAdd(&out_ring[(size_t)cur * 256 + c], accv);
                            cur = s; accv = v;
                        } else accv += v;
                    }
                    if (cur >= 0) atomicAdd(&out_ring[(size_t)cur * 256 + c], accv);
                }
            }
        }
    }
}

// ---------------------------------------------------------------------------
// Finalize molecule embedding in-place: avg = sum/count, max decode
// ---------------------------------------------------------------------------
__global__ void finalize_kernel(float* __restrict__ out, const int* __restrict__ counts, int M)
{
    int tid = blockIdx.x * blockDim.x + threadIdx.x;
    if (tid >= M * 128) return;
    int m = tid >> 7, c = tid & 127;
    int cnt = counts[m];
    float denom = (cnt > 0) ? (float)cnt : 1.0f;
    float s  = out[(size_t)m * 256 + c];
    float mr = out[(size_t)m * 256 + 128 + c];
    out[(size_t)m * 256 + c] = s / denom;
    out[(size_t)m * 256 + 128 + c] = (cnt > 0) ? (mr - 2.0f) : 0.0f;
}

extern "C" void kernel_launch(void* const* d_in, const int* in_sizes, int n_in,
                              void* d_out, int out_size, void* d_ws, size_t ws_size,
                              hipStream_t stream) {
    const float* af = (const float*)d_in[0];
    const float* am = (const float*)d_in[1];
    const float* Wf = (const float*)d_in[2];
    const float* bfe = (const float*)d_in[3];
    const float* W1 = (const float*)d_in[4];
    const float* b1 = (const float*)d_in[5];
    const float* W2 = (const float*)d_in[6];
    const float* b2 = (const float*)d_in[7];
    const float* WL = (const float*)d_in[8];
    const float* bL = (const float*)d_in[9];
    const float* WR = (const float*)d_in[10];
    const float* bR = (const float*)d_in[11];
    const int* seg      = (const int*)d_in[12];
    const int* leaf_idx = (const int*)d_in[13];
    const int* ring_idx = (const int*)d_in[14];
    const int* ring_seg = (const int*)d_in[15];

    const int N   = in_sizes[0] / 39;   // 300000
    const int NL  = in_sizes[13];       // 50000
    const int NRE = in_sizes[14];       // 120000
    const int M   = 10000;
    const int NR  = 20000;

    float* out = (float*)d_out;
    float* out_mol  = out;
    float* out_leaf = out + (size_t)M * 256;
    float* out_ring = out + (size_t)M * 256 + (size_t)NL * 256;

    // ws layout (16B-aligned offsets)
    int* counts = (int*)d_ws;                                       // 40 KB
    unsigned short* WfF = (unsigned short*)((char*)d_ws + 40960);   // 16 KB
    unsigned short* W1F = (unsigned short*)((char*)d_ws + 57344);   // 96 KB
    unsigned short* W2F = (unsigned short*)((char*)d_ws + 155648);  // 32 KB
    unsigned short* WLF = (unsigned short*)((char*)d_ws + 188416);  // 160 KB
    unsigned short* WRF = (unsigned short*)((char*)d_ws + 352256);  // 160 KB

    hipMemsetAsync(out_mol, 0, (size_t)M * 256 * sizeof(float), stream);
    hipMemsetAsync(out_ring, 0, (size_t)NR * 256 * sizeof(float), stream);
    hipMemsetAsync(counts, 0, (size_t)M * sizeof(int), stream);

    prep_frag<<<(29696 + 255) / 256, 256, 0, stream>>>(
        Wf, W1, W2, WL, WR, WfF, W1F, W2F, WLF, WRF);

    const int NA = (N + 63) / 64;
    const int nLeafBlocks = (NL + 63) / 64;
    const int nRingBlocks = (NRE + 63) / 64;
    const int NG = nLeafBlocks + nRingBlocks;
    const int T  = NA + NG;

    fused_main<<<T, 256, 0, stream>>>(
        af, am, WfF, bfe, W1F, b1, W2F, b2, WLF, bL, WRF, bR,
        seg, leaf_idx, ring_idx, ring_seg,
        out_mol, counts, out_leaf, out_ring,
        N, NL, NRE, nLeafBlocks, NG, T);

    finalize_kernel<<<(M * 128 + 255) / 256, 256, 0, stream>>>(out_mol, counts, M);
}

// Round 14
// 234.520 us; speedup vs baseline: 1.1630x; 1.0322x over previous
//
#include <hip/hip_runtime.h>
#include <math.h>

typedef __attribute__((ext_vector_type(8))) short bf16x8;
typedef __attribute__((ext_vector_type(4))) float f32x4;

__device__ __forceinline__ unsigned short f2bf(float x) {
    unsigned int u = __float_as_uint(x);
    u += 0x7fff + ((u >> 16) & 1);           // RNE
    return (unsigned short)(u >> 16);
}
__device__ __forceinline__ float bf2f(unsigned short b) {
    return __uint_as_float(((unsigned int)b) << 16);
}
__device__ __forceinline__ unsigned int cvtpk(float a, float b) {
    unsigned int r;
    asm("v_cvt_pk_bf16_f32 %0, %1, %2" : "=v"(r) : "v"(a), "v"(b));
    return r;
}
__device__ __forceinline__ float fast_tanh(float x) {
    float e = __expf(2.0f * x);
    return 1.0f - 2.0f / (e + 1.0f);
}
__device__ __forceinline__ f32x4 mfma16(bf16x8 a, bf16x8 b, f32x4 c) {
    return __builtin_amdgcn_mfma_f32_16x16x32_bf16(a, b, c, 0, 0, 0);
}
union bfu { unsigned int w[4]; bf16x8 v; };
__device__ __forceinline__ bf16x8 cvt8(float4 u, float4 v) {
    bfu x;
    x.w[0] = cvtpk(u.x, u.y); x.w[1] = cvtpk(u.z, u.w);
    x.w[2] = cvtpk(v.x, v.y); x.w[3] = cvtpk(v.z, v.w);
    return x.v;
}
__device__ __forceinline__ void async16(void* lds, const void* g) {
    __builtin_amdgcn_global_load_lds(
        (const __attribute__((address_space(1))) unsigned int*)g,
        (__attribute__((address_space(3))) unsigned int*)lds, 16, 0, 0);
}

#define SBAR0 __builtin_amdgcn_sched_barrier(0)
#define BARX(vm) do { SBAR0; \
    asm volatile("s_waitcnt vmcnt(" #vm ") lgkmcnt(0)" ::: "memory"); \
    __builtin_amdgcn_s_barrier(); SBAR0; } while (0)

// ---------------------------------------------------------------------------
// Prep + zero: weights -> frag-major bf16 (R11 layout) AND zero out_mol /
// out_ring / counts (replaces 3 hipMemsetAsync launches; float4 stores).
// Thread map: g < 29696 -> weight prep; else zero-region float4 index.
// ---------------------------------------------------------------------------
__global__ void prep_and_zero(const float* __restrict__ Wf, const float* __restrict__ W1,
                              const float* __restrict__ W2, const float* __restrict__ WL,
                              const float* __restrict__ WR,
                              unsigned short* __restrict__ WfF, unsigned short* __restrict__ W1F,
                              unsigned short* __restrict__ W2F, unsigned short* __restrict__ WLF,
                              unsigned short* __restrict__ WRF,
                              float* __restrict__ out_mol, float* __restrict__ out_ring,
                              int* __restrict__ counts, int M, int NR)
{
    int g = blockIdx.x * 256 + threadIdx.x;
    if (g >= 29696) {
        // ---- zeroing section (float4 granularity) ----
        int z = g - 29696;
        const int nMol  = M * 64;            // M*256 floats / 4
        const int nRing = NR * 64;           // NR*256 floats / 4
        const int nCnt  = (M + 3) / 4;       // M ints / 4
        float4 zf = {0.f, 0.f, 0.f, 0.f};
        if (z < nMol) {
            ((float4*)out_mol)[z] = zf;
        } else if ((z -= nMol) < nRing) {
            ((float4*)out_ring)[z] = zf;
        } else if ((z -= nRing) < nCnt) {
            ((float4*)counts)[z] = zf;       // M divisible by 4 (10000)
        }
        return;
    }
    int lane = g & 63, slot = g >> 6;
    int l15 = lane & 15, lkk = lane >> 4;

    unsigned short* dst;
    const float* W;
    int sl, NT, mode, Klim;
    if (slot < 16)       { dst = WfF; W = Wf; sl = slot;       NT = 8;  mode = 0; Klim = 39;  }
    else if (slot < 112) { dst = W1F; W = W1; sl = slot - 16;  NT = 8;  mode = 0; Klim = 384; }
    else if (slot < 144) { dst = W2F; W = W2; sl = slot - 112; NT = 8;  mode = 0; Klim = 128; }
    else if (slot < 304) { dst = WLF; W = WL; sl = slot - 144; NT = 16; mode = 1; Klim = 0;   }
    else                 { dst = WRF; W = WR; sl = slot - 304; NT = 16; mode = 1; Klim = 0;   }

    int ks = sl / NT;
    int n = (sl - ks * NT) * 16 + l15;
    int kb = ks * 32 + lkk * 8;
    unsigned short* o = dst + ((size_t)sl * 64 + lane) * 8;
    #pragma unroll
    for (int j = 0; j < 8; ++j) {
        int k = kb + j;
        float v;
        if (mode == 0) {
            v = (k < Klim) ? W[(size_t)k * 128 + n] : 0.0f;
        } else {
            if (k < 256)      v = W[(size_t)(39 + k) * 256 + n];
            else if (k < 295) v = W[(size_t)(k - 256) * 256 + n];
            else              v = 0.0f;
        }
        o[j] = f2bf(v);
    }
}

// ---------------------------------------------------------------------------
// Fused main: Bresenham-interleaved atom / gather blocks, 4 blocks/CU.
// (Byte-identical to R11/R13 — best measured: fused ~258 us.)
// ---------------------------------------------------------------------------
__global__ __launch_bounds__(256, 4) void fused_main(
    const float* __restrict__ af, const float* __restrict__ am,
    const unsigned short* __restrict__ WfF, const float* __restrict__ bfe,
    const unsigned short* __restrict__ W1F, const float* __restrict__ b1,
    const unsigned short* __restrict__ W2F, const float* __restrict__ b2,
    const unsigned short* __restrict__ WLF, const float* __restrict__ bL,
    const unsigned short* __restrict__ WRF, const float* __restrict__ bR,
    const int* __restrict__ seg, const int* __restrict__ leaf_idx,
    const int* __restrict__ ring_idx, const int* __restrict__ rseg,
    float* __restrict__ out_mol, int* __restrict__ counts,
    float* __restrict__ out_leaf, float* __restrict__ out_ring,
    int N, int NL, int NRE, int nLeafBlocks, int NG, int T)
{
    __shared__ alignas(16) unsigned char LDSb[32768];   // atom: Ebuf|Mbuf; gather: X tile
    __shared__ alignas(16) unsigned short Fb[2688];     // af tile [64][40] + pads
    __shared__ int sseg[64];

    const int t = threadIdx.x, lane = t & 63, w = t >> 6;
    const int lrow = lane & 15, lk = lane >> 4;

    const unsigned long long bid = blockIdx.x;
    const int g_before = (int)(bid * (unsigned long long)NG / (unsigned long long)T);
    const int g_after  = (int)((bid + 1ull) * (unsigned long long)NG / (unsigned long long)T);
    const bool is_gather = (g_after > g_before);

    if (!is_gather) {
        // ================= ATOM PATH =================
        const int ablk = (int)bid - g_before;
        const int r0 = ablk * 64;
        const int wr = w >> 1, wc = w & 1;
        unsigned char* Ebuf = LDSb;            // E tile, then H tile
        unsigned char* Mbuf = LDSb + 16384;    // 2x8KB chunks, then O
        unsigned char* M0 = Mbuf;
        unsigned char* M1 = Mbuf + 8192;

        auto stage8 = [&](unsigned char* buf, int cc) {
            #pragma unroll
            for (int p = 0; p < 2; ++p) {
                int i = t + p * 256;
                int r = i >> 3, sgl = i & 7;
                const float* src = am + ((size_t)min(r0 + r, N - 1) << 8)
                                      + cc * 32 + ((sgl ^ (r & 7)) << 2);
                async16(buf + (size_t)(p * 256 + w * 64) * 16, src);
            }
        };
        auto ldwb = [&](bf16x8* dst, const unsigned short* WB, int ks) {
            const bf16x8* Wp = (const bf16x8*)WB + ((size_t)ks * 8 + wc * 4) * 64 + lane;
            #pragma unroll
            for (int nt = 0; nt < 4; ++nt) dst[nt] = Wp[nt * 64];
        };
        auto cchunk = [&](const unsigned char* buf, const bf16x8* wbv, f32x4 (&acc)[2][4]) {
            #pragma unroll
            for (int mt = 0; mt < 2; ++mt) {
                int row = wr * 32 + mt * 16 + lrow;
                int s0 = (lk * 2) ^ (row & 7), s1 = (lk * 2 + 1) ^ (row & 7);
                float4 x0 = *(const float4*)(buf + row * 128 + (s0 << 4));
                float4 x1 = *(const float4*)(buf + row * 128 + (s1 << 4));
                bf16x8 a = cvt8(x0, x1);
                #pragma unroll
                for (int nt = 0; nt < 4; ++nt) acc[mt][nt] = mfma16(a, wbv[nt], acc[mt][nt]);
            }
        };
        auto tstep = [&](const unsigned char* buf, int ks, const bf16x8* wbv, f32x4 (&acc)[2][4]) {
            #pragma unroll
            for (int mt = 0; mt < 2; ++mt) {
                int row = wr * 32 + mt * 16 + lrow;
                int sg = (ks * 4 + lk) ^ (row & 15);
                bf16x8 a = *(const bf16x8*)(buf + row * 256 + (sg << 4));
                #pragma unroll
                for (int nt = 0; nt < 4; ++nt) acc[mt][nt] = mfma16(a, wbv[nt], acc[mt][nt]);
            }
        };
        auto tile_write = [&](unsigned char* buf, int row, int c, float v) {
            int byte = row * 256 + ((((c >> 3) ^ (row & 15))) << 4) + (c & 7) * 2;
            *(unsigned short*)(buf + byte) = f2bf(v);
        };

        // ---- prologue: contiguous af block load (oldest VMEM), weights, seg ----
        float afv[10];
        #pragma unroll
        for (int p = 0; p < 10; ++p) {
            int i = t + p * 256;
            size_t g = (size_t)r0 * 39 + i;
            afv[p] = (i < 2496 && g < (size_t)N * 39) ? af[g] : 0.f;
        }
        bf16x8 wf[2][4];
        ldwb(wf[0], WfF, 0);
        ldwb(wf[1], WfF, 1);
        float bfe_r[4], b1_r[4], b2_r[4];
        #pragma unroll
        for (int nt = 0; nt < 4; ++nt) {
            int c = wc * 64 + nt * 16 + lrow;
            bfe_r[nt] = bfe[c]; b1_r[nt] = b1[c]; b2_r[nt] = b2[c];
        }
        if (t < 64) sseg[t] = (r0 + t < N) ? seg[r0 + t] : -1;
        bf16x8 wbA[4], wbB[4];
        ldwb(wbA, W1F, 0);
        SBAR0;
        stage8(M0, 0);                 // newest VMEM: 4 asyncs stay in flight
        stage8(M1, 1);
        SBAR0;
        // write af tile (forces af retirements; asyncs are newer -> unaffected)
        #pragma unroll
        for (int p = 0; p < 10; ++p) {
            int i = t + p * 256;
            if (i < 2496) { int rf = i / 39, kf = i - rf * 39; Fb[rf * 40 + kf] = f2bf(afv[p]); }
        }
        if (t < 64) Fb[t * 40 + 39] = 0;
        if (t < 128) Fb[2560 + t] = 0;
        BARX(4);   // Fb visible; c0,c1 in flight

        // ---- phase 1: E = relu(af @ Wf + bf) -> Ebuf (A-frags from Fb) ----
        {
            f32x4 acc1[2][4] = {};
            #pragma unroll
            for (int ks = 0; ks < 2; ++ks) {
                bf16x8 a0 = *(const bf16x8*)((const unsigned char*)Fb
                              + (wr * 32 + lrow) * 80 + ks * 64 + lk * 16);
                bf16x8 a1 = *(const bf16x8*)((const unsigned char*)Fb
                              + (wr * 32 + 16 + lrow) * 80 + ks * 64 + lk * 16);
                #pragma unroll
                for (int nt = 0; nt < 4; ++nt) {
                    acc1[0][nt] = mfma16(a0, wf[ks][nt], acc1[0][nt]);
                    acc1[1][nt] = mfma16(a1, wf[ks][nt], acc1[1][nt]);
                }
            }
            #pragma unroll
            for (int nt = 0; nt < 4; ++nt) {
                int c = wc * 64 + nt * 16 + lrow;
                #pragma unroll
                for (int mt = 0; mt < 2; ++mt)
                    #pragma unroll
                    for (int rr = 0; rr < 4; ++rr) {
                        int row = wr * 32 + mt * 16 + lk * 4 + rr;
                        tile_write(Ebuf, row, c, fmaxf(acc1[mt][nt][rr] + bfe_r[nt], 0.f));
                    }
            }
        }
        BARX(4);   // E visible; c0,c1 still in flight

        // ---- phase 2: H = relu([E | msg] @ W1 + b1) ----
        f32x4 acc2[2][4] = {};
        ldwb(wbB, W1F, 1); SBAR0; tstep(Ebuf, 0, wbA, acc2);
        ldwb(wbA, W1F, 2); SBAR0; tstep(Ebuf, 1, wbB, acc2);
        ldwb(wbB, W1F, 3); SBAR0; tstep(Ebuf, 2, wbA, acc2);
        ldwb(wbA, W1F, 4); SBAR0; tstep(Ebuf, 3, wbB, acc2);
        BARX(4);

        ldwb(wbB, W1F, 5);  SBAR0; cchunk(M0, wbA, acc2);
        BARX(4); stage8(M0, 2); SBAR0;
        ldwb(wbA, W1F, 6);  SBAR0; cchunk(M1, wbB, acc2);
        BARX(4); stage8(M1, 3); SBAR0;
        ldwb(wbB, W1F, 7);  SBAR0; cchunk(M0, wbA, acc2);
        BARX(4); stage8(M0, 4); SBAR0;
        ldwb(wbA, W1F, 8);  SBAR0; cchunk(M1, wbB, acc2);
        BARX(4); stage8(M1, 5); SBAR0;
        ldwb(wbB, W1F, 9);  SBAR0; cchunk(M0, wbA, acc2);
        BARX(4); stage8(M0, 6); SBAR0;
        ldwb(wbA, W1F, 10); SBAR0; cchunk(M1, wbB, acc2);
        BARX(4); stage8(M1, 7); SBAR0;
        ldwb(wbB, W1F, 11); SBAR0; cchunk(M0, wbA, acc2);
        BARX(4);
        ldwb(wbA, W2F, 0);  SBAR0; cchunk(M1, wbB, acc2);

        // ---- H epilogue -> Ebuf (E dead) ----
        #pragma unroll
        for (int nt = 0; nt < 4; ++nt) {
            int c = wc * 64 + nt * 16 + lrow;
            #pragma unroll
            for (int mt = 0; mt < 2; ++mt)
                #pragma unroll
                for (int rr = 0; rr < 4; ++rr) {
                    int row = wr * 32 + mt * 16 + lk * 4 + rr;
                    tile_write(Ebuf, row, c, fmaxf(acc2[mt][nt][rr] + b1_r[nt], 0.f));
                }
        }
        BARX(4);   // H visible; W2F ks0 frags in flight

        // ---- phase 3: O = tanh(H @ W2 + b2) -> Mbuf overlay ----
        {
            f32x4 acc3[2][4] = {};
            ldwb(wbB, W2F, 1); SBAR0; tstep(Ebuf, 0, wbA, acc3);
            ldwb(wbA, W2F, 2); SBAR0; tstep(Ebuf, 1, wbB, acc3);
            ldwb(wbB, W2F, 3); SBAR0; tstep(Ebuf, 2, wbA, acc3);
            tstep(Ebuf, 3, wbB, acc3);
            #pragma unroll
            for (int nt = 0; nt < 4; ++nt) {
                int c = wc * 64 + nt * 16 + lrow;
                #pragma unroll
                for (int mt = 0; mt < 2; ++mt)
                    #pragma unroll
                    for (int rr = 0; rr < 4; ++rr) {
                        int row = wr * 32 + mt * 16 + lk * 4 + rr;
                        tile_write(Mbuf, row, c, fast_tanh(acc3[mt][nt][rr] + b2_r[nt]));
                    }
            }
        }
        asm volatile("s_waitcnt lgkmcnt(0)" ::: "memory");
        SBAR0;

        // ---- pooling ----
        {
            const int c = wc * 64 + lane;
            int cur = -1, runlen = 0;
            float s = 0.f, m = 0.f;
            #pragma unroll 1
            for (int a2 = 0; a2 < 32; ++a2) {
                int arow = wr * 32 + a2;
                int sg = sseg[arow];
                if (sg < 0) break;
                int byte = arow * 256 + ((((c >> 3) ^ (arow & 15))) << 4) + (c & 7) * 2;
                float v = bf2f(*(const unsigned short*)(Mbuf + byte));
                if (sg != cur) {
                    if (cur >= 0) {
                        atomicAdd(&out_mol[(size_t)cur * 256 + c], s);
                        atomicMax((unsigned int*)&out_mol[(size_t)cur * 256 + 128 + c],
                                  __float_as_uint(m + 2.0f));
                        if (wc == 0 && lane == 0) atomicAdd(&counts[cur], runlen);
                    }
                    cur = sg; s = v; m = v; runlen = 1;
                } else {
                    s += v; m = fmaxf(m, v); ++runlen;
                }
            }
            if (cur >= 0) {
                atomicAdd(&out_mol[(size_t)cur * 256 + c], s);
                atomicMax((unsigned int*)&out_mol[(size_t)cur * 256 + 128 + c],
                          __float_as_uint(m + 2.0f));
                if (wc == 0 && lane == 0) atomicAdd(&counts[cur], runlen);
            }
        }
        return;
    }

    // ================= GATHER PATH (leaf / ring) =================
    {
        const int gblk = g_before;
        const bool ring = gblk >= nLeafBlocks;
        const unsigned short* WF = ring ? WRF : WLF;
        const float* bv = ring ? bR : bL;
        const int* idx = ring ? ring_idx : leaf_idx;
        const int NROWS = ring ? NRE : NL;
        const int blk = ring ? gblk - nLeafBlocks : gblk;
        const int r0 = blk * 64;
        const int wrg = w & 1, wcg = w >> 1;      // rows wrg*32, cols wcg*128

        if (t < 64) sseg[t] = idx[min(r0 + t, NROWS - 1)];
        __syncthreads();

        // ---- stage msg rows -> swizzled bf16 X tile (row-contiguous loads) ----
        unsigned char* Xb = LDSb;
        #pragma unroll
        for (int p = 0; p < 16; ++p) {
            int i = t + p * 256;
            int r = i >> 6, kq = i & 63;
            float4 v = *(const float4*)(am + ((size_t)sseg[r] << 8) + kq * 4);
            uint2 u;
            u.x = cvtpk(v.x, v.y); u.y = cvtpk(v.z, v.w);
            *(uint2*)(Xb + r * 512 + (((kq >> 1) ^ (r & 15)) << 4) + (kq & 1) * 8) = u;
        }
        // ---- stage af rows -> Fb tile ----
        #pragma unroll
        for (int p = 0; p < 10; ++p) {
            int i = t + p * 256;
            if (i < 2496) {
                int rf = i / 39, kf = i - rf * 39;
                Fb[rf * 40 + kf] = f2bf(af[(size_t)sseg[rf] * 39 + kf]);
            }
        }
        if (t < 64) Fb[t * 40 + 39] = 0;
        if (t < 128) Fb[2560 + t] = 0;
        __syncthreads();

        f32x4 acc[2][8] = {};
        #pragma unroll
        for (int ks = 0; ks < 8; ++ks) {          // msg K-part from LDS
            bf16x8 wb[8];
            const bf16x8* B = (const bf16x8*)WF + (ks * 16 + wcg * 8) * 64 + lane;
            #pragma unroll
            for (int nt = 0; nt < 8; ++nt) wb[nt] = B[nt * 64];
            #pragma unroll
            for (int mt = 0; mt < 2; ++mt) {
                int row = wrg * 32 + mt * 16 + lrow;
                bf16x8 a = *(const bf16x8*)(Xb + row * 512 + ((((ks * 4 + lk) ^ (row & 15))) << 4));
                #pragma unroll
                for (int nt = 0; nt < 8; ++nt) acc[mt][nt] = mfma16(a, wb[nt], acc[mt][nt]);
            }
        }
        #pragma unroll
        for (int ks = 8; ks < 10; ++ks) {         // af K-part from Fb
            bf16x8 wb[8];
            const bf16x8* B = (const bf16x8*)WF + (ks * 16 + wcg * 8) * 64 + lane;
            #pragma unroll
            for (int nt = 0; nt < 8; ++nt) wb[nt] = B[nt * 64];
            #pragma unroll
            for (int mt = 0; mt < 2; ++mt) {
                int row = wrg * 32 + mt * 16 + lrow;
                bf16x8 a = *(const bf16x8*)((const unsigned char*)Fb
                              + row * 80 + (ks - 8) * 64 + lk * 16);
                #pragma unroll
                for (int nt = 0; nt < 8; ++nt) acc[mt][nt] = mfma16(a, wb[nt], acc[mt][nt]);
            }
        }

        if (!ring) {
            #pragma unroll
            for (int nt = 0; nt < 8; ++nt) {
                int c = wcg * 128 + nt * 16 + lrow;
                float bias = bv[c];
                #pragma unroll
                for (int mt = 0; mt < 2; ++mt) {
                    #pragma unroll
                    for (int r = 0; r < 4; ++r) {
                        int row = r0 + wrg * 32 + mt * 16 + lk * 4 + r;
                        if (row < NROWS)
                            out_leaf[(size_t)row * 256 + c] = fast_tanh(acc[mt][nt][r] + bias);
                    }
                }
            }
        } else {
            int sg[2][4];
            #pragma unroll
            for (int mt = 0; mt < 2; ++mt)
                #pragma unroll
                for (int r = 0; r < 4; ++r) {
                    int rr = r0 + wrg * 32 + mt * 16 + lk * 4 + r;
                    sg[mt][r] = (rr < NROWS) ? rseg[rr] : -1;
                }
            #pragma unroll
            for (int nt = 0; nt < 8; ++nt) {
                int c = wcg * 128 + nt * 16 + lrow;
                float bias = bv[c];
                #pragma unroll
                for (int mt = 0; mt < 2; ++mt) {
                    int cur = -1; float accv = 0.0f;
                    #pragma unroll
                    for (int r = 0; r < 4; ++r) {
                        float v = fast_tanh(acc[mt][nt][r] + bias);
                        int s = sg[mt][r];
                        if (s != cur) {
                            if (cur >= 0) atomicAdd(&out_ring[(size_t)cur * 256 + c], accv);
                            cur = s; accv = v;
                        } else accv += v;
                    }
                    if (cur >= 0) atomicAdd(&out_ring[(size_t)cur * 256 + c], accv);
                }
            }
        }
    }
}

// ---------------------------------------------------------------------------
// Finalize (float4-vectorized): avg = sum/count, max decode. 4 ch/thread.
// ---------------------------------------------------------------------------
__global__ void finalize_kernel(float* __restrict__ out, const int* __restrict__ counts, int M)
{
    int tid = blockIdx.x * blockDim.x + threadIdx.x;
    if (tid >= M * 32) return;
    int m = tid >> 5, c4 = tid & 31;
    int cnt = counts[m];
    float denom = (cnt > 0) ? (float)cnt : 1.0f;
    float inv = 1.0f / denom;
    float4 s  = *(float4*)&out[(size_t)m * 256 + c4 * 4];
    float4 mr = *(float4*)&out[(size_t)m * 256 + 128 + c4 * 4];
    s.x *= inv; s.y *= inv; s.z *= inv; s.w *= inv;
    if (cnt > 0) { mr.x -= 2.0f; mr.y -= 2.0f; mr.z -= 2.0f; mr.w -= 2.0f; }
    else         { mr.x = mr.y = mr.z = mr.w = 0.0f; }
    *(float4*)&out[(size_t)m * 256 + c4 * 4] = s;
    *(float4*)&out[(size_t)m * 256 + 128 + c4 * 4] = mr;
}

extern "C" void kernel_launch(void* const* d_in, const int* in_sizes, int n_in,
                              void* d_out, int out_size, void* d_ws, size_t ws_size,
                              hipStream_t stream) {
    const float* af = (const float*)d_in[0];
    const float* am = (const float*)d_in[1];
    const float* Wf = (const float*)d_in[2];
    const float* bfe = (const float*)d_in[3];
    const float* W1 = (const float*)d_in[4];
    const float* b1 = (const float*)d_in[5];
    const float* W2 = (const float*)d_in[6];
    const float* b2 = (const float*)d_in[7];
    const float* WL = (const float*)d_in[8];
    const float* bL = (const float*)d_in[9];
    const float* WR = (const float*)d_in[10];
    const float* bR = (const float*)d_in[11];
    const int* seg      = (const int*)d_in[12];
    const int* leaf_idx = (const int*)d_in[13];
    const int* ring_idx = (const int*)d_in[14];
    const int* ring_seg = (const int*)d_in[15];

    const int N   = in_sizes[0] / 39;   // 300000
    const int NL  = in_sizes[13];       // 50000
    const int NRE = in_sizes[14];       // 120000
    const int M   = 10000;
    const int NR  = 20000;

    float* out = (float*)d_out;
    float* out_mol  = out;
    float* out_leaf = out + (size_t)M * 256;
    float* out_ring = out + (size_t)M * 256 + (size_t)NL * 256;

    // ws layout (16B-aligned offsets)
    int* counts = (int*)d_ws;                                       // 40 KB
    unsigned short* WfF = (unsigned short*)((char*)d_ws + 40960);   // 16 KB
    unsigned short* W1F = (unsigned short*)((char*)d_ws + 57344);   // 96 KB
    unsigned short* W2F = (unsigned short*)((char*)d_ws + 155648);  // 32 KB
    unsigned short* WLF = (unsigned short*)((char*)d_ws + 188416);  // 160 KB
    unsigned short* WRF = (unsigned short*)((char*)d_ws + 352256);  // 160 KB

    // one prep launch: weight repack + zero out_mol / out_ring / counts
    const int nZero = M * 64 + NR * 64 + (M + 3) / 4;   // float4 units
    const int prepT = 29696 + nZero;
    prep_and_zero<<<(prepT + 255) / 256, 256, 0, stream>>>(
        Wf, W1, W2, WL, WR, WfF, W1F, W2F, WLF, WRF,
        out_mol, out_ring, counts, M, NR);

    const int NA = (N + 63) / 64;
    const int nLeafBlocks = (NL + 63) / 64;
    const int nRingBlocks = (NRE + 63) / 64;
    const int NG = nLeafBlocks + nRingBlocks;
    const int T  = NA + NG;

    fused_main<<<T, 256, 0, stream>>>(
        af, am, WfF, bfe, W1F, b1, W2F, b2, WLF, bL, WRF, bR,
        seg, leaf_idx, ring_idx, ring_seg,
        out_mol, counts, out_leaf, out_ring,
        N, NL, NRE, nLeafBlocks, NG, T);

    finalize_kernel<<<(M * 32 + 255) / 256, 256, 0, stream>>>(out, counts, M);
}